// Round 10
// baseline (518.893 us; speedup 1.0000x reference)
//
#include <hip/hip_runtime.h>
#include <hip/hip_bf16.h>

#define NN 50000
#define NE 800000
#define H 128
#define DE 16
#define BN_EPS 1e-5f
#define NB_E 3125     // NE/256 exact (edgehead grid)
#define NBKT 196      // node-range buckets (256 nodes each)
#define NBLK 256      // edge chunks
#define EPB 3125      // NE/NBLK edges per chunk

typedef float v2f __attribute__((ext_vector_type(2)));
typedef float v4f __attribute__((ext_vector_type(4)));
typedef short bfrag __attribute__((ext_vector_type(8)));   // 8 bf16 = 4 VGPRs

__device__ __forceinline__ unsigned int packbf2(float a, float b) {
    __hip_bfloat162 h = __float22bfloat162_rn(make_float2(a, b));
    return *(unsigned int*)&h;
}
__device__ __forceinline__ v2f unpackbf2(unsigned int u) {
    v2f r;
    r.x = __uint_as_float(u << 16);
    r.y = __uint_as_float(u & 0xffff0000u);
    return r;
}
__device__ __forceinline__ bfrag cvt8(float4 a0, float4 a1) {
    union { uint4 u; bfrag f; } x;
    x.u.x = packbf2(a0.x, a0.y);
    x.u.y = packbf2(a0.z, a0.w);
    x.u.z = packbf2(a1.x, a1.y);
    x.u.w = packbf2(a1.z, a1.w);
    return x.f;
}
__device__ __forceinline__ bfrag cvt8v(v4f a0, v4f a1) {
    union { uint4 u; bfrag f; } x;
    x.u.x = packbf2(a0.x, a0.y);
    x.u.y = packbf2(a0.z, a0.w);
    x.u.z = packbf2(a1.x, a1.y);
    x.u.w = packbf2(a1.z, a1.w);
    return x.f;
}
#define COMP(u4, j) ((j) == 0 ? (u4).x : (j) == 1 ? (u4).y : (j) == 2 ? (u4).z : (u4).w)

// 16-lane add-reduce via DPP row_ror (VALU-only)
__device__ __forceinline__ float dpp_rowred16(float s) {
    s += __int_as_float(__builtin_amdgcn_update_dpp(0, __float_as_int(s), 0x121, 0xf, 0xf, false));
    s += __int_as_float(__builtin_amdgcn_update_dpp(0, __float_as_int(s), 0x122, 0xf, 0xf, false));
    s += __int_as_float(__builtin_amdgcn_update_dpp(0, __float_as_int(s), 0x124, 0xf, 0xf, false));
    s += __int_as_float(__builtin_amdgcn_update_dpp(0, __float_as_int(s), 0x128, 0xf, 0xf, false));
    return s;
}

// ---------------- Phase A: per-chunk LDS bucket histogram || weight preconvert ----
__global__ __launch_bounds__(256) void phaseA_k(const int* __restrict__ dst,
                                                int* __restrict__ bhist,
                                                const float* __restrict__ W1,
                                                const float* __restrict__ W2,
                                                const float* __restrict__ Ws,
                                                const float* __restrict__ Wd,
                                                const float* __restrict__ We,
                                                short* __restrict__ d1, short* __restrict__ d2,
                                                short* __restrict__ ds_, short* __restrict__ dd,
                                                unsigned int* __restrict__ WePk) {
    int b = blockIdx.x;
    if (b < NBLK) {
        __shared__ int lh[256];
        lh[threadIdx.x] = 0;
        __syncthreads();
        int base = b * EPB;
        for (int e = threadIdx.x; e < EPB; e += 256)
            atomicAdd(&lh[dst[base + e] >> 8], 1);
        __syncthreads();
        if (threadIdx.x < NBKT)
            bhist[threadIdx.x * NBLK + b] = lh[threadIdx.x];
        return;
    }
    b -= NBLK;
    if (b < 256) {
        int mat = b >> 6;
        const float* s = mat == 0 ? W1 : mat == 1 ? W2 : mat == 2 ? Ws : Wd;
        short* d = mat == 0 ? d1 : mat == 1 ? d2 : mat == 2 ? ds_ : dd;
        int idx = (b & 63) * 256 + threadIdx.x;   // 16384
        int n = idx & 127, k = idx >> 7;
        float v = s[k * 128 + n];
        d[n * 128 + k] = (short)(packbf2(v, v) & 0xffff);
    } else {
        int idx = (b - 256) * 256 + threadIdx.x;  // 0..2047
        int c = idx >> 8;
        int lane = (idx >> 2) & 63;
        int j2 = (idx & 3) * 2;
        int q = lane >> 4, i = lane & 15;
        int k0 = q * 8 + j2, k1 = k0 + 1;
        int feat = i * 8 + c;
        float v0 = (k0 < 16) ? We[k0 * 128 + feat] : 0.f;
        float v1 = (k1 < 16) ? We[k1 * 128 + feat] : 0.f;
        WePk[idx] = packbf2(v0, v1);
    }
}

// ---------------- Phase B: bucket scan + in-place rebase (1 block) ----------------
__global__ void phaseB_k(int* __restrict__ bhist, int* __restrict__ bucketBase,
                         int* __restrict__ bucketTot) {
    __shared__ int sh[256];
    int t = threadIdx.x;
    int tot = 0;
    if (t < NBKT)
        for (int blk = 0; blk < NBLK; blk++) tot += bhist[t * NBLK + blk];
    sh[t] = tot;
    __syncthreads();
    for (int off = 1; off < 256; off <<= 1) {
        int v = (t >= off) ? sh[t - off] : 0;
        __syncthreads();
        sh[t] += v;
        __syncthreads();
    }
    if (t < NBKT) {
        int base = sh[t] - tot;
        bucketBase[t] = base;
        bucketTot[t] = tot;
        int run = base;
        for (int blk = 0; blk < NBLK; blk++) {
            int h = bhist[t * NBLK + blk];
            bhist[t * NBLK + blk] = run;
            run += h;
        }
    }
}

// ---------------- Phase C: scatter edges into bucket-contiguous tmp (512 thr) ------
__global__ __launch_bounds__(512) void phaseC_k(const int* __restrict__ src,
                                                const int* __restrict__ dst,
                                                const int* __restrict__ bhist,
                                                unsigned int* __restrict__ tmp) {
    __shared__ int lcur[256];
    int b = blockIdx.x;
    if (threadIdx.x < NBKT)
        lcur[threadIdx.x] = bhist[threadIdx.x * NBLK + b];
    __syncthreads();
    int base = b * EPB;
    for (int e = threadIdx.x; e < EPB; e += 512) {
        int d = dst[base + e];
        int s = src[base + e];
        int pos = atomicAdd(&lcur[d >> 8], 1);
        tmp[pos] = (unsigned int)s | ((unsigned int)(d & 255) << 16);
    }
}

// ---------------- Phase D: per-bucket CSR finalize (512 thr) ----------------
__global__ __launch_bounds__(512) void fillb_k(const int* __restrict__ bucketBase,
                                               const int* __restrict__ bucketTot,
                                               const unsigned int* __restrict__ tmp,
                                               int* __restrict__ counts,
                                               int* __restrict__ offsets,
                                               float* __restrict__ dinv,
                                               int* __restrict__ srcs) {
    __shared__ int hist[256], off[256];
    int t = threadIdx.x;
    int b = blockIdx.x;
    if (t < 256) hist[t] = 0;
    __syncthreads();
    int base = bucketBase[b];
    int tot = bucketTot[b];
    const unsigned int* tp = tmp + base;
    for (int idx = t; idx < tot; idx += 512)
        atomicAdd(&hist[tp[idx] >> 16], 1);
    __syncthreads();
    int h = 0;
    if (t < 256) { h = hist[t]; off[t] = h; }
    __syncthreads();
    for (int o = 1; o < 256; o <<= 1) {
        int v = (t < 256 && t >= o) ? off[t - o] : 0;
        __syncthreads();
        if (t < 256) off[t] += v;
        __syncthreads();
    }
    if (t < 256) {
        int excl = off[t] - h;
        int node = b * 256 + t;
        if (node < NN) {
            counts[node] = h;
            offsets[node] = base + excl;
            dinv[node] = rsqrtf((float)h + 1.0f);
        }
        hist[t] = excl;    // reuse as per-node cursor
    }
    __syncthreads();
    for (int idx = t; idx < tot; idx += 512) {
        unsigned int u = tp[idx];
        int pos = atomicAdd(&hist[u >> 16], 1);
        srcs[base + pos] = (int)(u & 0xffffu);
    }
}

// ---------------- conv1 MFMA GEMM: hs1 = bf16((x @ W1) * dinv) ----------------
__global__ __launch_bounds__(256) void gemm1_k(const float* __restrict__ A,
                                               const short* __restrict__ Bt,
                                               unsigned int* __restrict__ Cb,
                                               const float* __restrict__ rowScale) {
    int lane = threadIdx.x & 63;
    int w = threadIdx.x >> 6;
    int i = lane & 15;
    int q = lane >> 4;
    int r0 = blockIdx.x * 64 + w * 16;
    int arow = min(r0 + i, NN - 1);
    const float* Arow = A + (size_t)arow * 128;

    v4f acc[8];
#pragma unroll
    for (int c = 0; c < 8; c++) acc[c] = (v4f)0.f;

#pragma unroll
    for (int kc = 0; kc < 128; kc += 32) {
        int kb = kc + q * 8;
        float4 a0 = *(const float4*)&Arow[kb];
        float4 a1 = *(const float4*)&Arow[kb + 4];
        bfrag af = cvt8(a0, a1);
#pragma unroll
        for (int c = 0; c < 8; c++) {
            bfrag bf = *(const bfrag*)&Bt[(size_t)(c * 16 + i) * 128 + kb];
            acc[c] = __builtin_amdgcn_mfma_f32_16x16x32_bf16(af, bf, acc[c], 0, 0, 0);
        }
    }

    int orow0 = r0 + q * 4;
    v4f ds = *(const v4f*)&rowScale[min(orow0, NN - 4)];
#pragma unroll
    for (int c = 0; c < 8; c++) {
        int col = c * 16 + i;
#pragma unroll
        for (int r = 0; r < 4; r++) {
            float v = acc[c][r] * ds[r];
            float vp = __shfl_xor(v, 1, 64);
            if (!(i & 1) && orow0 + r < NN)
                Cb[(size_t)(orow0 + r) * 64 + (col >> 1)] = packbf2(v, vp);
        }
    }
}

// ---------------- conv2 GEMM with BN-final fused in prologue ----------------
__global__ __launch_bounds__(256) void gemm_bn_k(const unsigned int* __restrict__ Ab,
                                                 const short* __restrict__ Bt,
                                                 unsigned int* __restrict__ Cb,
                                                 const float* __restrict__ rowScale,
                                                 const float* __restrict__ sums,
                                                 const float* __restrict__ sumsq,
                                                 const float* __restrict__ gamma,
                                                 const float* __restrict__ beta) {
    __shared__ __align__(16) float tAs[128], tCs[128];
    if (threadIdx.x < 128) {
        int f = threadIdx.x;
        float mean = sums[f] * (1.0f / NN);
        float var = sumsq[f] * (1.0f / NN) - mean * mean;
        float a = gamma[f] * rsqrtf(var + BN_EPS);
        tAs[f] = a;
        tCs[f] = beta[f] - mean * a;
    }
    __syncthreads();

    int lane = threadIdx.x & 63;
    int w = threadIdx.x >> 6;
    int i = lane & 15;
    int q = lane >> 4;
    int r0 = blockIdx.x * 64 + w * 16;
    int arow = min(r0 + i, NN - 1);

    v4f acc[8];
#pragma unroll
    for (int c = 0; c < 8; c++) acc[c] = (v4f)0.f;

#pragma unroll
    for (int kc = 0; kc < 128; kc += 32) {
        int kb = kc + q * 8;
        uint4 u = *(const uint4*)&Ab[(size_t)arow * 64 + (kb >> 1)];
        v2f z0 = unpackbf2(u.x), z1 = unpackbf2(u.y);
        v2f z2 = unpackbf2(u.z), z3 = unpackbf2(u.w);
        v2f t0 = *(const v2f*)&tAs[kb],     c0 = *(const v2f*)&tCs[kb];
        v2f t1 = *(const v2f*)&tAs[kb + 2], c1 = *(const v2f*)&tCs[kb + 2];
        v2f t2 = *(const v2f*)&tAs[kb + 4], c2 = *(const v2f*)&tCs[kb + 4];
        v2f t3 = *(const v2f*)&tAs[kb + 6], c3 = *(const v2f*)&tCs[kb + 6];
        z0 = z0 * t0 + c0; z1 = z1 * t1 + c1;
        z2 = z2 * t2 + c2; z3 = z3 * t3 + c3;
        union { uint4 u; bfrag f; } x;
        x.u.x = packbf2(fmaxf(z0.x, 0.f), fmaxf(z0.y, 0.f));
        x.u.y = packbf2(fmaxf(z1.x, 0.f), fmaxf(z1.y, 0.f));
        x.u.z = packbf2(fmaxf(z2.x, 0.f), fmaxf(z2.y, 0.f));
        x.u.w = packbf2(fmaxf(z3.x, 0.f), fmaxf(z3.y, 0.f));
        bfrag af = x.f;
#pragma unroll
        for (int c = 0; c < 8; c++) {
            bfrag bf = *(const bfrag*)&Bt[(size_t)(c * 16 + i) * 128 + kb];
            acc[c] = __builtin_amdgcn_mfma_f32_16x16x32_bf16(af, bf, acc[c], 0, 0, 0);
        }
    }

    int orow0 = r0 + q * 4;
    v4f ds = *(const v4f*)&rowScale[min(orow0, NN - 4)];
#pragma unroll
    for (int c = 0; c < 8; c++) {
        int col = c * 16 + i;
#pragma unroll
        for (int r = 0; r < 4; r++) {
            float v = acc[c][r] * ds[r];
            float vp = __shfl_xor(v, 1, 64);
            if (!(i & 1) && orow0 + r < NN)
                Cb[(size_t)(orow0 + r) * 64 + (col >> 1)] = packbf2(v, vp);
        }
    }
}

// ---------------- merged P/Q MFMA GEMM (A bf16-packed): P=A@Bs (bf16), Q=A@Bd+bm1 (bf16) ----
__global__ __launch_bounds__(256) void gemm_pq(const unsigned int* __restrict__ zbA,
                                               const short* __restrict__ Bs_,
                                               const short* __restrict__ Bd_,
                                               const float* __restrict__ bm1,
                                               unsigned int* __restrict__ Pb,
                                               unsigned int* __restrict__ Qb,
                                               int M) {
    int lane = threadIdx.x & 63;
    int w = threadIdx.x >> 6;
    int i = lane & 15;
    int q = lane >> 4;
    int r0 = blockIdx.x * 64 + w * 16;
    int arow = min(r0 + i, M - 1);

    v4f accP[8], accQ[8];
#pragma unroll
    for (int c = 0; c < 8; c++) { accP[c] = (v4f)0.f; accQ[c] = (v4f)0.f; }

#pragma unroll
    for (int kc = 0; kc < 128; kc += 32) {
        int kb = kc + q * 8;
        bfrag af = *(const bfrag*)&zbA[(size_t)arow * 64 + (kb >> 1)];
#pragma unroll
        for (int c = 0; c < 8; c++) {
            bfrag bs = *(const bfrag*)&Bs_[(size_t)(c * 16 + i) * 128 + kb];
            bfrag bd = *(const bfrag*)&Bd_[(size_t)(c * 16 + i) * 128 + kb];
            accP[c] = __builtin_amdgcn_mfma_f32_16x16x32_bf16(af, bs, accP[c], 0, 0, 0);
            accQ[c] = __builtin_amdgcn_mfma_f32_16x16x32_bf16(af, bd, accQ[c], 0, 0, 0);
        }
    }

    int orow0 = r0 + q * 4;
    float bm1c[8];
#pragma unroll
    for (int c = 0; c < 8; c++) bm1c[c] = bm1[c * 16 + i];
#pragma unroll
    for (int c = 0; c < 8; c++) {
        int col = c * 16 + i;
#pragma unroll
        for (int r = 0; r < 4; r++) {
            float vP = accP[c][r];
            float vPp = __shfl_xor(vP, 1, 64);
            float vQ = accQ[c][r] + bm1c[c];
            float vQp = __shfl_xor(vQ, 1, 64);
            if (!(i & 1) && orow0 + r < M) {
                Pb[(size_t)(orow0 + r) * 64 + (col >> 1)] = packbf2(vP, vPp);
                Qb[(size_t)(orow0 + r) * 64 + (col >> 1)] = packbf2(vQ, vQp);
            }
        }
    }
}

// ---------------- sliced aggregation ----------------
// z[n][f] = dinv[n]*(sum_{e->n} hs[src][f] + hs[n][f]) + b[f] is per-feature
// separable, so the kernel is launched 4x (sl=0..3), each pass gathering only a
// 64B feature-slice of every row. Live table footprint per pass = 50000*64B =
// 3.2MB (< 4MB per-XCD L2) -> the ~140MB of L2-fill traffic from thrashing the
// 12.8MB table collapses to ~26MB of cold fills. Gather shape: lane=(row=lane>>2,
// c=lane&3): 16 edges x 64B per instruction, one full cache line per edge-slice.
// All __shfl under FULL exec (round-4 lesson).
__global__ __launch_bounds__(256) void aggslice_k(const unsigned int* __restrict__ hsb,
                                                  const int* __restrict__ offsets,
                                                  const int* __restrict__ counts,
                                                  const int* __restrict__ srcs,
                                                  const float* __restrict__ dinv,
                                                  const float* __restrict__ bias,
                                                  unsigned int* __restrict__ zbout,
                                                  int sl) {
    int lane = threadIdx.x & 63;
    int row = lane >> 2;   // edge within 16-group
    int c = lane & 3;      // 16B sub-slice
    int n = __builtin_amdgcn_readfirstlane(blockIdx.x * 4 + (threadIdx.x >> 6));
    if (n >= NN) return;
    int beg = offsets[n];
    int cnt = counts[n];
    const unsigned int* hcol = hsb + sl * 16 + c * 4;
    v2f a0 = {0.f, 0.f}, a1 = {0.f, 0.f}, a2 = {0.f, 0.f}, a3 = {0.f, 0.f};
    for (int cc = 0; cc < cnt; cc += 64) {
        int vsrc = srcs[beg + cc + lane];
        int m = min(64, cnt - cc);
        int ng = m >> 4;
        for (int g = 0; g < ng; g++) {
            int sr = __shfl(vsrc, g * 16 + row, 64);
            uint4 u = *(const uint4*)&hcol[(size_t)sr * 64];
            a0 += unpackbf2(u.x); a1 += unpackbf2(u.y);
            a2 += unpackbf2(u.z); a3 += unpackbf2(u.w);
        }
        int rem = m & 15;
        if (rem) {
            int sr = __shfl(vsrc, (m & ~15) + row, 64);   // FULL-exec shfl
            if (row < rem) {
                uint4 u = *(const uint4*)&hcol[(size_t)sr * 64];
                a0 += unpackbf2(u.x); a1 += unpackbf2(u.y);
                a2 += unpackbf2(u.z); a3 += unpackbf2(u.w);
            }
        }
    }
    // reduce across the 16 rows (stride-4 lane groups)
#pragma unroll
    for (int off = 4; off <= 32; off <<= 1) {
        a0.x += __shfl_xor(a0.x, off, 64); a0.y += __shfl_xor(a0.y, off, 64);
        a1.x += __shfl_xor(a1.x, off, 64); a1.y += __shfl_xor(a1.y, off, 64);
        a2.x += __shfl_xor(a2.x, off, 64); a2.y += __shfl_xor(a2.y, off, 64);
        a3.x += __shfl_xor(a3.x, off, 64); a3.y += __shfl_xor(a3.y, off, 64);
    }
    if (row == 0) {   // lanes 0..3 write the 64B output slice
        uint4 su = *(const uint4*)&hcol[(size_t)n * 64];
        v2f s0 = unpackbf2(su.x), s1 = unpackbf2(su.y);
        v2f s2 = unpackbf2(su.z), s3 = unpackbf2(su.w);
        float di = dinv[n];
        int fb = sl * 32 + c * 8;
        float4 b0 = *(const float4*)&bias[fb];
        float4 b1 = *(const float4*)&bias[fb + 4];
        uint4 o;
        o.x = packbf2((a0.x + s0.x) * di + b0.x, (a0.y + s0.y) * di + b0.y);
        o.y = packbf2((a1.x + s1.x) * di + b0.z, (a1.y + s1.y) * di + b0.w);
        o.z = packbf2((a2.x + s2.x) * di + b1.x, (a2.y + s2.y) * di + b1.y);
        o.w = packbf2((a3.x + s3.x) * di + b1.z, (a3.y + s3.y) * di + b1.w);
        *(uint4*)&zbout[(size_t)n * 64 + sl * 16 + c * 4] = o;
    }
}

// ---------------- BatchNorm stats (bf16-packed input) ----------------
__global__ __launch_bounds__(256) void bnstats_b_k(const unsigned int* __restrict__ zb,
                                                   float* __restrict__ sums,
                                                   float* __restrict__ sumsq) {
    __shared__ v2f ls[4][64], lq[4][64];
    int lane = threadIdx.x & 63;   // feature pair
    int sub = threadIdx.x >> 6;    // 4 rows in parallel
    v2f s = {0.f, 0.f}, q = {0.f, 0.f};
    for (int r = blockIdx.x * 4 + sub; r < NN; r += gridDim.x * 4) {
        v2f v = unpackbf2(zb[(size_t)r * 64 + lane]);
        s += v;
        q += v * v;
    }
    if (sub) { ls[sub][lane] = s; lq[sub][lane] = q; }
    __syncthreads();
    if (!sub) {
        s += ls[1][lane] + ls[2][lane] + ls[3][lane];
        q += lq[1][lane] + lq[2][lane] + lq[3][lane];
        atomicAdd(&sums[lane * 2], s.x);
        atomicAdd(&sums[lane * 2 + 1], s.y);
        atomicAdd(&sumsq[lane * 2], q.x);
        atomicAdd(&sumsq[lane * 2 + 1], q.y);
    }
}

// ---------------- edge head: MFMA in ORIGINAL edge order (round-8 verbatim) --------
// r9 lesson: bundled changes (2 groups/wave + non-NT store) regressed 65.6->91.6us
// despite lower write bytes -> write path was not critical; reverted to the
// measured-good r8 structure (1 group of 64 edges per wave, NT out stores).
__global__ __launch_bounds__(256) void edgehead_k(const unsigned int* __restrict__ Pb,
                                                  const unsigned int* __restrict__ Qb,
                                                  const float* __restrict__ ea,
                                                  const int* __restrict__ srcI,
                                                  const int* __restrict__ dstI,
                                                  const unsigned int* __restrict__ WePk,
                                                  const float* __restrict__ Wm2,
                                                  const float* __restrict__ bm2,
                                                  float* __restrict__ out) {
    int lane = threadIdx.x & 63;
    int wid = threadIdx.x >> 6;
    int base = (blockIdx.x * 4 + wid) * 64;
    int i = lane & 15;
    int q = lane >> 4;

    bfrag wef[8];
#pragma unroll
    for (int c = 0; c < 8; c++)
        wef[c] = *(const bfrag*)&WePk[(c * 64 + lane) * 4];
    float4 wv0 = *(const float4*)&Wm2[i * 8];
    float4 wv1 = *(const float4*)&Wm2[i * 8 + 4];
    v2f wv2[4];
    wv2[0].x = wv0.x; wv2[0].y = wv0.y;
    wv2[1].x = wv0.z; wv2[1].y = wv0.w;
    wv2[2].x = wv1.x; wv2[2].y = wv1.y;
    wv2[3].x = wv1.z; wv2[3].y = wv1.w;
    float bm2v = bm2[0];

    int sv = srcI[base + lane];
    int dv = dstI[base + lane];

#pragma unroll
    for (int t = 0; t < 4; t++) {
        int tb = t * 16;
        bfrag af;
#pragma unroll
        for (int z = 0; z < 8; z++) af[z] = 0;
        if (q < 2) {
            const float* erow = &ea[(size_t)(base + tb + i) * 16 + q * 8];
            v4f e0 = __builtin_nontemporal_load((const v4f*)erow);
            v4f e1 = __builtin_nontemporal_load((const v4f*)(erow + 4));
            af = cvt8v(e0, e1);
        }
        uint4 Pu[4], Qu[4];
#pragma unroll
        for (int r = 0; r < 4; r++) {
            int sr = __shfl(sv, tb + q * 4 + r, 64);
            int dr = __shfl(dv, tb + q * 4 + r, 64);
            Pu[r] = *(const uint4*)&Pb[(size_t)sr * 64 + i * 4];
            Qu[r] = *(const uint4*)&Qb[(size_t)dr * 64 + i * 4];
        }
        v4f acc[8];
#pragma unroll
        for (int c = 0; c < 8; c++) acc[c] = (v4f)0.f;
#pragma unroll
        for (int c = 0; c < 8; c++)
            acc[c] = __builtin_amdgcn_mfma_f32_16x16x32_bf16(af, wef[c], acc[c], 0, 0, 0);
#pragma unroll
        for (int r = 0; r < 4; r++) {
            v2f sa = {0.f, 0.f};
#pragma unroll
            for (int j = 0; j < 4; j++) {
                v2f pq = unpackbf2(COMP(Pu[r], j)) + unpackbf2(COMP(Qu[r], j));
                v2f tt;
                tt.x = acc[2 * j][r] + pq.x;
                tt.y = acc[2 * j + 1][r] + pq.y;
                tt.x = fmaxf(tt.x, 0.f);
                tt.y = fmaxf(tt.y, 0.f);
                sa += tt * wv2[j];
            }
            float s = dpp_rowred16(sa.x + sa.y);
            if (i == 0) __builtin_nontemporal_store(s + bm2v, &out[base + tb + q * 4 + r]);
        }
    }
}

// ---------------- launcher ----------------
extern "C" void kernel_launch(void* const* d_in, const int* in_sizes, int n_in,
                              void* d_out, int out_size, void* d_ws, size_t ws_size,
                              hipStream_t stream) {
    const float* x     = (const float*)d_in[0];
    const int*   ei    = (const int*)d_in[1];
    const float* ea    = (const float*)d_in[2];
    const float* W1    = (const float*)d_in[3];
    const float* b1    = (const float*)d_in[4];
    const float* gamma = (const float*)d_in[5];
    const float* beta  = (const float*)d_in[6];
    const float* W2    = (const float*)d_in[7];
    const float* b2    = (const float*)d_in[8];
    const float* Wm1   = (const float*)d_in[9];
    const float* bm1   = (const float*)d_in[10];
    const float* Wm2   = (const float*)d_in[11];
    const float* bm2   = (const float*)d_in[12];
    float* out = (float*)d_out;

    const int* srcI = ei;
    const int* dstI = ei + NE;

    char* w = (char*)d_ws;
    auto alloc = [&](size_t bytes) {
        char* p = w;
        w += (bytes + 255) & ~(size_t)255;
        return p;
    };
    // zero region: sums | sumsq — one small memset
    float* sums    = (float*)alloc(256 * 4);
    float* sumsq   = sums + 128;
    int*   bhist   = (int*)alloc(NBKT * NBLK * 4);     // 200 KB
    int*   bucketBase = (int*)alloc(NBKT * 4);
    int*   bucketTot  = (int*)alloc(NBKT * 4);
    unsigned int* tmp = (unsigned int*)alloc((size_t)NE * 4);   // 3.2 MB
    int*   counts  = (int*)alloc(NN * 4);
    int*   offsets = (int*)alloc(NN * 4);
    float* dinv    = (float*)alloc(NN * 4);
    int*   srcs    = (int*)alloc((size_t)(NE + 64) * 4);
    short* bt1     = (short*)alloc(128 * 128 * 2);
    short* bt2     = (short*)alloc(128 * 128 * 2);
    short* bts     = (short*)alloc(128 * 128 * 2);
    short* btd     = (short*)alloc(128 * 128 * 2);
    unsigned int* WePk = (unsigned int*)alloc(2048 * 4);
    unsigned int* hsb  = (unsigned int*)alloc((size_t)NN * 64 * 4);   // hs / P table
    unsigned int* zb1  = (unsigned int*)alloc((size_t)NN * 64 * 4);   // z1 bf16; later z2 (aliased)
    unsigned int* Qb   = (unsigned int*)alloc((size_t)NN * 64 * 4);   // Q table
    unsigned int* zb2  = zb1;   // alias: z1 dead after conv2 GEMM reads it

    hipMemsetAsync(sums, 0, 256 * 4, stream);

    // K1: per-chunk bucket histograms || weight preconvert
    phaseA_k<<<NBLK + 264, 256, 0, stream>>>(dstI, bhist, W1, W2, Wm1,
                                             Wm1 + 128 * 128, Wm1 + 256 * 128,
                                             bt1, bt2, bts, btd, WePk);
    // K2: bucket scan + rebase
    phaseB_k<<<1, 256, 0, stream>>>(bhist, bucketBase, bucketTot);
    // K3: scatter to bucket-contiguous tmp (no global atomics)
    phaseC_k<<<NBLK, 512, 0, stream>>>(srcI, dstI, bhist, tmp);
    // K4: per-bucket CSR finalize (counts/offsets/dinv/srcs)
    fillb_k<<<NBKT, 512, 0, stream>>>(bucketBase, bucketTot, tmp,
                                      counts, offsets, dinv, srcs);

    const int GB = (NN + 63) / 64;   // 782
    const int AGG = (NN + 3) / 4;    // 12500

    // K5: conv1 GEMM (hs1 = (x@W1)*dinv -> bf16)
    gemm1_k<<<GB, 256, 0, stream>>>(x, bt1, hsb, dinv);
    // K6: agg1 -> z1 (bf16), 4 sequential feature-slice passes
    for (int sl = 0; sl < 4; sl++)
        aggslice_k<<<AGG, 256, 0, stream>>>(hsb, offsets, counts, srcs, dinv, b1,
                                            zb1, sl);
    // K7: BN stats
    bnstats_b_k<<<256, 256, 0, stream>>>(zb1, sums, sumsq);
    // K8: conv2 GEMM, BN-final fused in prologue
    gemm_bn_k<<<GB, 256, 0, stream>>>(zb1, bt2, hsb, dinv, sums, sumsq, gamma, beta);
    // K9: agg2 -> z2 (aliases zb1), 4 slice passes
    for (int sl = 0; sl < 4; sl++)
        aggslice_k<<<AGG, 256, 0, stream>>>(hsb, offsets, counts, srcs, dinv, b2,
                                            zb2, sl);
    // K10: edge head precompute P/Q
    gemm_pq<<<GB, 256, 0, stream>>>(zb2, bts, btd, bm1, hsb, Qb, NN);
    // K11: edge head (r8 structure: 256 edges/block)
    edgehead_k<<<NB_E, 256, 0, stream>>>(hsb, Qb, ea, srcI, dstI, WePk,
                                         Wm2, bm2, out);
}

// Round 11
// 513.608 us; speedup vs baseline: 1.0103x; 1.0103x over previous
//
#include <hip/hip_runtime.h>
#include <hip/hip_bf16.h>

#define NN 50000
#define NE 800000
#define H 128
#define DE 16
#define BN_EPS 1e-5f
#define NB_E 3125     // NE/256 exact (edgehead grid)
#define NBKT 196      // node-range buckets (256 nodes each)
#define NBLK 256      // edge chunks
#define EPB 3125      // NE/NBLK edges per chunk
#define SLN ((size_t)NN * 16)   // uints per feature-slice in sliced hs layout

typedef float v2f __attribute__((ext_vector_type(2)));
typedef float v4f __attribute__((ext_vector_type(4)));
typedef short bfrag __attribute__((ext_vector_type(8)));   // 8 bf16 = 4 VGPRs

__device__ __forceinline__ unsigned int packbf2(float a, float b) {
    __hip_bfloat162 h = __float22bfloat162_rn(make_float2(a, b));
    return *(unsigned int*)&h;
}
__device__ __forceinline__ v2f unpackbf2(unsigned int u) {
    v2f r;
    r.x = __uint_as_float(u << 16);
    r.y = __uint_as_float(u & 0xffff0000u);
    return r;
}
__device__ __forceinline__ bfrag cvt8(float4 a0, float4 a1) {
    union { uint4 u; bfrag f; } x;
    x.u.x = packbf2(a0.x, a0.y);
    x.u.y = packbf2(a0.z, a0.w);
    x.u.z = packbf2(a1.x, a1.y);
    x.u.w = packbf2(a1.z, a1.w);
    return x.f;
}
__device__ __forceinline__ bfrag cvt8v(v4f a0, v4f a1) {
    union { uint4 u; bfrag f; } x;
    x.u.x = packbf2(a0.x, a0.y);
    x.u.y = packbf2(a0.z, a0.w);
    x.u.z = packbf2(a1.x, a1.y);
    x.u.w = packbf2(a1.z, a1.w);
    return x.f;
}
#define COMP(u4, j) ((j) == 0 ? (u4).x : (j) == 1 ? (u4).y : (j) == 2 ? (u4).z : (u4).w)

// 16-lane add-reduce via DPP row_ror (VALU-only)
__device__ __forceinline__ float dpp_rowred16(float s) {
    s += __int_as_float(__builtin_amdgcn_update_dpp(0, __float_as_int(s), 0x121, 0xf, 0xf, false));
    s += __int_as_float(__builtin_amdgcn_update_dpp(0, __float_as_int(s), 0x122, 0xf, 0xf, false));
    s += __int_as_float(__builtin_amdgcn_update_dpp(0, __float_as_int(s), 0x124, 0xf, 0xf, false));
    s += __int_as_float(__builtin_amdgcn_update_dpp(0, __float_as_int(s), 0x128, 0xf, 0xf, false));
    return s;
}

// ---------------- Phase A: per-chunk LDS bucket histogram || weight preconvert ----
__global__ __launch_bounds__(256) void phaseA_k(const int* __restrict__ dst,
                                                int* __restrict__ bhist,
                                                const float* __restrict__ W1,
                                                const float* __restrict__ W2,
                                                const float* __restrict__ Ws,
                                                const float* __restrict__ Wd,
                                                const float* __restrict__ We,
                                                short* __restrict__ d1, short* __restrict__ d2,
                                                short* __restrict__ ds_, short* __restrict__ dd,
                                                unsigned int* __restrict__ WePk) {
    int b = blockIdx.x;
    if (b < NBLK) {
        __shared__ int lh[256];
        lh[threadIdx.x] = 0;
        __syncthreads();
        int base = b * EPB;
        for (int e = threadIdx.x; e < EPB; e += 256)
            atomicAdd(&lh[dst[base + e] >> 8], 1);
        __syncthreads();
        if (threadIdx.x < NBKT)
            bhist[threadIdx.x * NBLK + b] = lh[threadIdx.x];
        return;
    }
    b -= NBLK;
    if (b < 256) {
        int mat = b >> 6;
        const float* s = mat == 0 ? W1 : mat == 1 ? W2 : mat == 2 ? Ws : Wd;
        short* d = mat == 0 ? d1 : mat == 1 ? d2 : mat == 2 ? ds_ : dd;
        int idx = (b & 63) * 256 + threadIdx.x;   // 16384
        int n = idx & 127, k = idx >> 7;
        float v = s[k * 128 + n];
        d[n * 128 + k] = (short)(packbf2(v, v) & 0xffff);
    } else {
        int idx = (b - 256) * 256 + threadIdx.x;  // 0..2047
        int c = idx >> 8;
        int lane = (idx >> 2) & 63;
        int j2 = (idx & 3) * 2;
        int q = lane >> 4, i = lane & 15;
        int k0 = q * 8 + j2, k1 = k0 + 1;
        int feat = i * 8 + c;
        float v0 = (k0 < 16) ? We[k0 * 128 + feat] : 0.f;
        float v1 = (k1 < 16) ? We[k1 * 128 + feat] : 0.f;
        WePk[idx] = packbf2(v0, v1);
    }
}

// ---------------- Phase B: bucket scan + in-place rebase (1 block) ----------------
__global__ void phaseB_k(int* __restrict__ bhist, int* __restrict__ bucketBase,
                         int* __restrict__ bucketTot) {
    __shared__ int sh[256];
    int t = threadIdx.x;
    int tot = 0;
    if (t < NBKT)
        for (int blk = 0; blk < NBLK; blk++) tot += bhist[t * NBLK + blk];
    sh[t] = tot;
    __syncthreads();
    for (int off = 1; off < 256; off <<= 1) {
        int v = (t >= off) ? sh[t - off] : 0;
        __syncthreads();
        sh[t] += v;
        __syncthreads();
    }
    if (t < NBKT) {
        int base = sh[t] - tot;
        bucketBase[t] = base;
        bucketTot[t] = tot;
        int run = base;
        for (int blk = 0; blk < NBLK; blk++) {
            int h = bhist[t * NBLK + blk];
            bhist[t * NBLK + blk] = run;
            run += h;
        }
    }
}

// ---------------- Phase C: scatter edges into bucket-contiguous tmp (512 thr) ------
__global__ __launch_bounds__(512) void phaseC_k(const int* __restrict__ src,
                                                const int* __restrict__ dst,
                                                const int* __restrict__ bhist,
                                                unsigned int* __restrict__ tmp) {
    __shared__ int lcur[256];
    int b = blockIdx.x;
    if (threadIdx.x < NBKT)
        lcur[threadIdx.x] = bhist[threadIdx.x * NBLK + b];
    __syncthreads();
    int base = b * EPB;
    for (int e = threadIdx.x; e < EPB; e += 512) {
        int d = dst[base + e];
        int s = src[base + e];
        int pos = atomicAdd(&lcur[d >> 8], 1);
        tmp[pos] = (unsigned int)s | ((unsigned int)(d & 255) << 16);
    }
}

// ---------------- Phase D: per-bucket CSR finalize (512 thr) ----------------
__global__ __launch_bounds__(512) void fillb_k(const int* __restrict__ bucketBase,
                                               const int* __restrict__ bucketTot,
                                               const unsigned int* __restrict__ tmp,
                                               int* __restrict__ counts,
                                               int* __restrict__ offsets,
                                               float* __restrict__ dinv,
                                               int* __restrict__ srcs) {
    __shared__ int hist[256], off[256];
    int t = threadIdx.x;
    int b = blockIdx.x;
    if (t < 256) hist[t] = 0;
    __syncthreads();
    int base = bucketBase[b];
    int tot = bucketTot[b];
    const unsigned int* tp = tmp + base;
    for (int idx = t; idx < tot; idx += 512)
        atomicAdd(&hist[tp[idx] >> 16], 1);
    __syncthreads();
    int h = 0;
    if (t < 256) { h = hist[t]; off[t] = h; }
    __syncthreads();
    for (int o = 1; o < 256; o <<= 1) {
        int v = (t < 256 && t >= o) ? off[t - o] : 0;
        __syncthreads();
        if (t < 256) off[t] += v;
        __syncthreads();
    }
    if (t < 256) {
        int excl = off[t] - h;
        int node = b * 256 + t;
        if (node < NN) {
            counts[node] = h;
            offsets[node] = base + excl;
            dinv[node] = rsqrtf((float)h + 1.0f);
        }
        hist[t] = excl;    // reuse as per-node cursor
    }
    __syncthreads();
    for (int idx = t; idx < tot; idx += 512) {
        unsigned int u = tp[idx];
        int pos = atomicAdd(&hist[u >> 16], 1);
        srcs[base + pos] = (int)(u & 0xffffu);
    }
}

// ---------------- conv1 MFMA GEMM: hs1 = bf16((x @ W1) * dinv), SLICED out ---------
// Output layout node-major sliced: hss[sl][node][16 uints] (sl = featpair>>4).
// The slice is a contiguous 3.2MB region -> aggregation passes are L2-resident
// with full set utilization (round-10 lesson: column-strided slices alias into
// 1/4 of the L2 sets and thrash).
__global__ __launch_bounds__(256) void gemm1_k(const float* __restrict__ A,
                                               const short* __restrict__ Bt,
                                               unsigned int* __restrict__ Cb,
                                               const float* __restrict__ rowScale) {
    int lane = threadIdx.x & 63;
    int w = threadIdx.x >> 6;
    int i = lane & 15;
    int q = lane >> 4;
    int r0 = blockIdx.x * 64 + w * 16;
    int arow = min(r0 + i, NN - 1);
    const float* Arow = A + (size_t)arow * 128;

    v4f acc[8];
#pragma unroll
    for (int c = 0; c < 8; c++) acc[c] = (v4f)0.f;

#pragma unroll
    for (int kc = 0; kc < 128; kc += 32) {
        int kb = kc + q * 8;
        float4 a0 = *(const float4*)&Arow[kb];
        float4 a1 = *(const float4*)&Arow[kb + 4];
        bfrag af = cvt8(a0, a1);
#pragma unroll
        for (int c = 0; c < 8; c++) {
            bfrag bf = *(const bfrag*)&Bt[(size_t)(c * 16 + i) * 128 + kb];
            acc[c] = __builtin_amdgcn_mfma_f32_16x16x32_bf16(af, bf, acc[c], 0, 0, 0);
        }
    }

    int orow0 = r0 + q * 4;
    v4f ds = *(const v4f*)&rowScale[min(orow0, NN - 4)];
#pragma unroll
    for (int c = 0; c < 8; c++) {
        int ui = (c * 16 + i) >> 1;
        size_t sbase = (size_t)(ui >> 4) * SLN + (ui & 15);
#pragma unroll
        for (int r = 0; r < 4; r++) {
            float v = acc[c][r] * ds[r];
            float vp = __shfl_xor(v, 1, 64);
            if (!(i & 1) && orow0 + r < NN)
                Cb[sbase + (size_t)(orow0 + r) * 16] = packbf2(v, vp);
        }
    }
}

// ---------------- conv2 GEMM with BN-final fused in prologue, SLICED out ----------
__global__ __launch_bounds__(256) void gemm_bn_k(const unsigned int* __restrict__ Ab,
                                                 const short* __restrict__ Bt,
                                                 unsigned int* __restrict__ Cb,
                                                 const float* __restrict__ rowScale,
                                                 const float* __restrict__ sums,
                                                 const float* __restrict__ sumsq,
                                                 const float* __restrict__ gamma,
                                                 const float* __restrict__ beta) {
    __shared__ __align__(16) float tAs[128], tCs[128];
    if (threadIdx.x < 128) {
        int f = threadIdx.x;
        float mean = sums[f] * (1.0f / NN);
        float var = sumsq[f] * (1.0f / NN) - mean * mean;
        float a = gamma[f] * rsqrtf(var + BN_EPS);
        tAs[f] = a;
        tCs[f] = beta[f] - mean * a;
    }
    __syncthreads();

    int lane = threadIdx.x & 63;
    int w = threadIdx.x >> 6;
    int i = lane & 15;
    int q = lane >> 4;
    int r0 = blockIdx.x * 64 + w * 16;
    int arow = min(r0 + i, NN - 1);

    v4f acc[8];
#pragma unroll
    for (int c = 0; c < 8; c++) acc[c] = (v4f)0.f;

#pragma unroll
    for (int kc = 0; kc < 128; kc += 32) {
        int kb = kc + q * 8;
        uint4 u = *(const uint4*)&Ab[(size_t)arow * 64 + (kb >> 1)];
        v2f z0 = unpackbf2(u.x), z1 = unpackbf2(u.y);
        v2f z2 = unpackbf2(u.z), z3 = unpackbf2(u.w);
        v2f t0 = *(const v2f*)&tAs[kb],     c0 = *(const v2f*)&tCs[kb];
        v2f t1 = *(const v2f*)&tAs[kb + 2], c1 = *(const v2f*)&tCs[kb + 2];
        v2f t2 = *(const v2f*)&tAs[kb + 4], c2 = *(const v2f*)&tCs[kb + 4];
        v2f t3 = *(const v2f*)&tAs[kb + 6], c3 = *(const v2f*)&tCs[kb + 6];
        z0 = z0 * t0 + c0; z1 = z1 * t1 + c1;
        z2 = z2 * t2 + c2; z3 = z3 * t3 + c3;
        union { uint4 u; bfrag f; } x;
        x.u.x = packbf2(fmaxf(z0.x, 0.f), fmaxf(z0.y, 0.f));
        x.u.y = packbf2(fmaxf(z1.x, 0.f), fmaxf(z1.y, 0.f));
        x.u.z = packbf2(fmaxf(z2.x, 0.f), fmaxf(z2.y, 0.f));
        x.u.w = packbf2(fmaxf(z3.x, 0.f), fmaxf(z3.y, 0.f));
        bfrag af = x.f;
#pragma unroll
        for (int c = 0; c < 8; c++) {
            bfrag bf = *(const bfrag*)&Bt[(size_t)(c * 16 + i) * 128 + kb];
            acc[c] = __builtin_amdgcn_mfma_f32_16x16x32_bf16(af, bf, acc[c], 0, 0, 0);
        }
    }

    int orow0 = r0 + q * 4;
    v4f ds = *(const v4f*)&rowScale[min(orow0, NN - 4)];
#pragma unroll
    for (int c = 0; c < 8; c++) {
        int ui = (c * 16 + i) >> 1;
        size_t sbase = (size_t)(ui >> 4) * SLN + (ui & 15);
#pragma unroll
        for (int r = 0; r < 4; r++) {
            float v = acc[c][r] * ds[r];
            float vp = __shfl_xor(v, 1, 64);
            if (!(i & 1) && orow0 + r < NN)
                Cb[sbase + (size_t)(orow0 + r) * 16] = packbf2(v, vp);
        }
    }
}

// ---------------- merged P/Q MFMA GEMM (row-major out, consumed by edgehead) -------
__global__ __launch_bounds__(256) void gemm_pq(const unsigned int* __restrict__ zbA,
                                               const short* __restrict__ Bs_,
                                               const short* __restrict__ Bd_,
                                               const float* __restrict__ bm1,
                                               unsigned int* __restrict__ Pb,
                                               unsigned int* __restrict__ Qb,
                                               int M) {
    int lane = threadIdx.x & 63;
    int w = threadIdx.x >> 6;
    int i = lane & 15;
    int q = lane >> 4;
    int r0 = blockIdx.x * 64 + w * 16;
    int arow = min(r0 + i, M - 1);

    v4f accP[8], accQ[8];
#pragma unroll
    for (int c = 0; c < 8; c++) { accP[c] = (v4f)0.f; accQ[c] = (v4f)0.f; }

#pragma unroll
    for (int kc = 0; kc < 128; kc += 32) {
        int kb = kc + q * 8;
        bfrag af = *(const bfrag*)&zbA[(size_t)arow * 64 + (kb >> 1)];
#pragma unroll
        for (int c = 0; c < 8; c++) {
            bfrag bs = *(const bfrag*)&Bs_[(size_t)(c * 16 + i) * 128 + kb];
            bfrag bd = *(const bfrag*)&Bd_[(size_t)(c * 16 + i) * 128 + kb];
            accP[c] = __builtin_amdgcn_mfma_f32_16x16x32_bf16(af, bs, accP[c], 0, 0, 0);
            accQ[c] = __builtin_amdgcn_mfma_f32_16x16x32_bf16(af, bd, accQ[c], 0, 0, 0);
        }
    }

    int orow0 = r0 + q * 4;
    float bm1c[8];
#pragma unroll
    for (int c = 0; c < 8; c++) bm1c[c] = bm1[c * 16 + i];
#pragma unroll
    for (int c = 0; c < 8; c++) {
        int col = c * 16 + i;
#pragma unroll
        for (int r = 0; r < 4; r++) {
            float vP = accP[c][r];
            float vPp = __shfl_xor(vP, 1, 64);
            float vQ = accQ[c][r] + bm1c[c];
            float vQp = __shfl_xor(vQ, 1, 64);
            if (!(i & 1) && orow0 + r < M) {
                Pb[(size_t)(orow0 + r) * 64 + (col >> 1)] = packbf2(vP, vPp);
                Qb[(size_t)(orow0 + r) * 64 + (col >> 1)] = packbf2(vQ, vQp);
            }
        }
    }
}

// ---------------- sliced aggregation (node-major slices) ----------------
// Pass sl gathers 64B rows from the contiguous 3.2MB slice hss[sl] (< 4MB per-XCD
// L2, full set utilization). Gather shape: lane=(row=lane>>2, c=lane&3): 16 edges
// x one 64B line per instruction. All __shfl under FULL exec (round-4 lesson).
__global__ __launch_bounds__(256) void aggslice_k(const unsigned int* __restrict__ hss,
                                                  const int* __restrict__ offsets,
                                                  const int* __restrict__ counts,
                                                  const int* __restrict__ srcs,
                                                  const float* __restrict__ dinv,
                                                  const float* __restrict__ bias,
                                                  unsigned int* __restrict__ zbout,
                                                  int sl) {
    int lane = threadIdx.x & 63;
    int row = lane >> 2;   // edge within 16-group
    int c = lane & 3;      // 16B sub-chunk of the 64B slice row
    int n = __builtin_amdgcn_readfirstlane(blockIdx.x * 4 + (threadIdx.x >> 6));
    if (n >= NN) return;
    int beg = offsets[n];
    int cnt = counts[n];
    const unsigned int* hcol = hss + (size_t)sl * SLN + c * 4;
    v2f a0 = {0.f, 0.f}, a1 = {0.f, 0.f}, a2 = {0.f, 0.f}, a3 = {0.f, 0.f};
    for (int cc = 0; cc < cnt; cc += 64) {
        int vsrc = srcs[beg + cc + lane];
        int m = min(64, cnt - cc);
        int ng = m >> 4;
        for (int g = 0; g < ng; g++) {
            int sr = __shfl(vsrc, g * 16 + row, 64);
            uint4 u = *(const uint4*)&hcol[(size_t)sr * 16];
            a0 += unpackbf2(u.x); a1 += unpackbf2(u.y);
            a2 += unpackbf2(u.z); a3 += unpackbf2(u.w);
        }
        int rem = m & 15;
        if (rem) {
            int sr = __shfl(vsrc, (m & ~15) + row, 64);   // FULL-exec shfl
            if (row < rem) {
                uint4 u = *(const uint4*)&hcol[(size_t)sr * 16];
                a0 += unpackbf2(u.x); a1 += unpackbf2(u.y);
                a2 += unpackbf2(u.z); a3 += unpackbf2(u.w);
            }
        }
    }
    // reduce across the 16 rows (stride-4 lane groups)
#pragma unroll
    for (int off = 4; off <= 32; off <<= 1) {
        a0.x += __shfl_xor(a0.x, off, 64); a0.y += __shfl_xor(a0.y, off, 64);
        a1.x += __shfl_xor(a1.x, off, 64); a1.y += __shfl_xor(a1.y, off, 64);
        a2.x += __shfl_xor(a2.x, off, 64); a2.y += __shfl_xor(a2.y, off, 64);
        a3.x += __shfl_xor(a3.x, off, 64); a3.y += __shfl_xor(a3.y, off, 64);
    }
    if (row == 0) {   // lanes 0..3 write the 64B output chunk of z's row
        uint4 su = *(const uint4*)&hcol[(size_t)n * 16];
        v2f s0 = unpackbf2(su.x), s1 = unpackbf2(su.y);
        v2f s2 = unpackbf2(su.z), s3 = unpackbf2(su.w);
        float di = dinv[n];
        int fb = sl * 32 + c * 8;
        float4 b0 = *(const float4*)&bias[fb];
        float4 b1 = *(const float4*)&bias[fb + 4];
        uint4 o;
        o.x = packbf2((a0.x + s0.x) * di + b0.x, (a0.y + s0.y) * di + b0.y);
        o.y = packbf2((a1.x + s1.x) * di + b0.z, (a1.y + s1.y) * di + b0.w);
        o.z = packbf2((a2.x + s2.x) * di + b1.x, (a2.y + s2.y) * di + b1.y);
        o.w = packbf2((a3.x + s3.x) * di + b1.z, (a3.y + s3.y) * di + b1.w);
        *(uint4*)&zbout[(size_t)n * 64 + sl * 16 + c * 4] = o;
    }
}

// ---------------- BatchNorm stats (bf16-packed row-major input) ----------------
__global__ __launch_bounds__(256) void bnstats_b_k(const unsigned int* __restrict__ zb,
                                                   float* __restrict__ sums,
                                                   float* __restrict__ sumsq) {
    __shared__ v2f ls[4][64], lq[4][64];
    int lane = threadIdx.x & 63;   // feature pair
    int sub = threadIdx.x >> 6;    // 4 rows in parallel
    v2f s = {0.f, 0.f}, q = {0.f, 0.f};
    for (int r = blockIdx.x * 4 + sub; r < NN; r += gridDim.x * 4) {
        v2f v = unpackbf2(zb[(size_t)r * 64 + lane]);
        s += v;
        q += v * v;
    }
    if (sub) { ls[sub][lane] = s; lq[sub][lane] = q; }
    __syncthreads();
    if (!sub) {
        s += ls[1][lane] + ls[2][lane] + ls[3][lane];
        q += lq[1][lane] + lq[2][lane] + lq[3][lane];
        atomicAdd(&sums[lane * 2], s.x);
        atomicAdd(&sums[lane * 2 + 1], s.y);
        atomicAdd(&sumsq[lane * 2], q.x);
        atomicAdd(&sumsq[lane * 2 + 1], q.y);
    }
}

// ---------------- edge head: MFMA in ORIGINAL edge order (round-8 verbatim) --------
__global__ __launch_bounds__(256) void edgehead_k(const unsigned int* __restrict__ Pb,
                                                  const unsigned int* __restrict__ Qb,
                                                  const float* __restrict__ ea,
                                                  const int* __restrict__ srcI,
                                                  const int* __restrict__ dstI,
                                                  const unsigned int* __restrict__ WePk,
                                                  const float* __restrict__ Wm2,
                                                  const float* __restrict__ bm2,
                                                  float* __restrict__ out) {
    int lane = threadIdx.x & 63;
    int wid = threadIdx.x >> 6;
    int base = (blockIdx.x * 4 + wid) * 64;
    int i = lane & 15;
    int q = lane >> 4;

    bfrag wef[8];
#pragma unroll
    for (int c = 0; c < 8; c++)
        wef[c] = *(const bfrag*)&WePk[(c * 64 + lane) * 4];
    float4 wv0 = *(const float4*)&Wm2[i * 8];
    float4 wv1 = *(const float4*)&Wm2[i * 8 + 4];
    v2f wv2[4];
    wv2[0].x = wv0.x; wv2[0].y = wv0.y;
    wv2[1].x = wv0.z; wv2[1].y = wv0.w;
    wv2[2].x = wv1.x; wv2[2].y = wv1.y;
    wv2[3].x = wv1.z; wv2[3].y = wv1.w;
    float bm2v = bm2[0];

    int sv = srcI[base + lane];
    int dv = dstI[base + lane];

#pragma unroll
    for (int t = 0; t < 4; t++) {
        int tb = t * 16;
        bfrag af;
#pragma unroll
        for (int z = 0; z < 8; z++) af[z] = 0;
        if (q < 2) {
            const float* erow = &ea[(size_t)(base + tb + i) * 16 + q * 8];
            v4f e0 = __builtin_nontemporal_load((const v4f*)erow);
            v4f e1 = __builtin_nontemporal_load((const v4f*)(erow + 4));
            af = cvt8v(e0, e1);
        }
        uint4 Pu[4], Qu[4];
#pragma unroll
        for (int r = 0; r < 4; r++) {
            int sr = __shfl(sv, tb + q * 4 + r, 64);
            int dr = __shfl(dv, tb + q * 4 + r, 64);
            Pu[r] = *(const uint4*)&Pb[(size_t)sr * 64 + i * 4];
            Qu[r] = *(const uint4*)&Qb[(size_t)dr * 64 + i * 4];
        }
        v4f acc[8];
#pragma unroll
        for (int c = 0; c < 8; c++) acc[c] = (v4f)0.f;
#pragma unroll
        for (int c = 0; c < 8; c++)
            acc[c] = __builtin_amdgcn_mfma_f32_16x16x32_bf16(af, wef[c], acc[c], 0, 0, 0);
#pragma unroll
        for (int r = 0; r < 4; r++) {
            v2f sa = {0.f, 0.f};
#pragma unroll
            for (int j = 0; j < 4; j++) {
                v2f pq = unpackbf2(COMP(Pu[r], j)) + unpackbf2(COMP(Qu[r], j));
                v2f tt;
                tt.x = acc[2 * j][r] + pq.x;
                tt.y = acc[2 * j + 1][r] + pq.y;
                tt.x = fmaxf(tt.x, 0.f);
                tt.y = fmaxf(tt.y, 0.f);
                sa += tt * wv2[j];
            }
            float s = dpp_rowred16(sa.x + sa.y);
            if (i == 0) __builtin_nontemporal_store(s + bm2v, &out[base + tb + q * 4 + r]);
        }
    }
}

// ---------------- launcher ----------------
extern "C" void kernel_launch(void* const* d_in, const int* in_sizes, int n_in,
                              void* d_out, int out_size, void* d_ws, size_t ws_size,
                              hipStream_t stream) {
    const float* x     = (const float*)d_in[0];
    const int*   ei    = (const int*)d_in[1];
    const float* ea    = (const float*)d_in[2];
    const float* W1    = (const float*)d_in[3];
    const float* b1    = (const float*)d_in[4];
    const float* gamma = (const float*)d_in[5];
    const float* beta  = (const float*)d_in[6];
    const float* W2    = (const float*)d_in[7];
    const float* b2    = (const float*)d_in[8];
    const float* Wm1   = (const float*)d_in[9];
    const float* bm1   = (const float*)d_in[10];
    const float* Wm2   = (const float*)d_in[11];
    const float* bm2   = (const float*)d_in[12];
    float* out = (float*)d_out;

    const int* srcI = ei;
    const int* dstI = ei + NE;

    char* w = (char*)d_ws;
    auto alloc = [&](size_t bytes) {
        char* p = w;
        w += (bytes + 255) & ~(size_t)255;
        return p;
    };
    // zero region: sums | sumsq — one small memset
    float* sums    = (float*)alloc(256 * 4);
    float* sumsq   = sums + 128;
    int*   bhist   = (int*)alloc(NBKT * NBLK * 4);     // 200 KB
    int*   bucketBase = (int*)alloc(NBKT * 4);
    int*   bucketTot  = (int*)alloc(NBKT * 4);
    unsigned int* tmp = (unsigned int*)alloc((size_t)NE * 4);   // 3.2 MB
    int*   counts  = (int*)alloc(NN * 4);
    int*   offsets = (int*)alloc(NN * 4);
    float* dinv    = (float*)alloc(NN * 4);
    int*   srcs    = (int*)alloc((size_t)(NE + 64) * 4);
    short* bt1     = (short*)alloc(128 * 128 * 2);
    short* bt2     = (short*)alloc(128 * 128 * 2);
    short* bts     = (short*)alloc(128 * 128 * 2);
    short* btd     = (short*)alloc(128 * 128 * 2);
    unsigned int* WePk = (unsigned int*)alloc(2048 * 4);
    unsigned int* hsb  = (unsigned int*)alloc((size_t)NN * 64 * 4);   // hs (sliced) / P table (row-major)
    unsigned int* zb1  = (unsigned int*)alloc((size_t)NN * 64 * 4);   // z1 bf16 row-major; later z2 (aliased)
    unsigned int* Qb   = (unsigned int*)alloc((size_t)NN * 64 * 4);   // Q table (row-major)
    unsigned int* zb2  = zb1;   // alias: z1 dead after conv2 GEMM reads it

    hipMemsetAsync(sums, 0, 256 * 4, stream);

    // K1: per-chunk bucket histograms || weight preconvert
    phaseA_k<<<NBLK + 264, 256, 0, stream>>>(dstI, bhist, W1, W2, Wm1,
                                             Wm1 + 128 * 128, Wm1 + 256 * 128,
                                             bt1, bt2, bts, btd, WePk);
    // K2: bucket scan + rebase
    phaseB_k<<<1, 256, 0, stream>>>(bhist, bucketBase, bucketTot);
    // K3: scatter to bucket-contiguous tmp (no global atomics)
    phaseC_k<<<NBLK, 512, 0, stream>>>(srcI, dstI, bhist, tmp);
    // K4: per-bucket CSR finalize (counts/offsets/dinv/srcs)
    fillb_k<<<NBKT, 512, 0, stream>>>(bucketBase, bucketTot, tmp,
                                      counts, offsets, dinv, srcs);

    const int GB = (NN + 63) / 64;   // 782
    const int AGG = (NN + 3) / 4;    // 12500

    // K5: conv1 GEMM (hs1 sliced)
    gemm1_k<<<GB, 256, 0, stream>>>(x, bt1, hsb, dinv);
    // K6: agg1 -> z1 (bf16 row-major), 4 L2-resident slice passes
    for (int sl = 0; sl < 4; sl++)
        aggslice_k<<<AGG, 256, 0, stream>>>(hsb, offsets, counts, srcs, dinv, b1,
                                            zb1, sl);
    // K7: BN stats
    bnstats_b_k<<<256, 256, 0, stream>>>(zb1, sums, sumsq);
    // K8: conv2 GEMM, BN-final fused in prologue (hs2 sliced)
    gemm_bn_k<<<GB, 256, 0, stream>>>(zb1, bt2, hsb, dinv, sums, sumsq, gamma, beta);
    // K9: agg2 -> z2 (aliases zb1), 4 slice passes
    for (int sl = 0; sl < 4; sl++)
        aggslice_k<<<AGG, 256, 0, stream>>>(hsb, offsets, counts, srcs, dinv, b2,
                                            zb2, sl);
    // K10: edge head precompute P/Q (row-major tables)
    gemm_pq<<<GB, 256, 0, stream>>>(zb2, bts, btd, bm1, hsb, Qb, NN);
    // K11: edge head (r8 structure: 256 edges/block)
    edgehead_k<<<NB_E, 256, 0, stream>>>(hsb, Qb, ea, srcI, dstI, WePk,
                                         Wm2, bm2, out);
}

// Round 12
// 400.998 us; speedup vs baseline: 1.2940x; 1.2808x over previous
//
#include <hip/hip_runtime.h>
#include <hip/hip_bf16.h>

#define NN 50000
#define NE 800000
#define H 128
#define DE 16
#define BN_EPS 1e-5f
#define NB_E 3125     // NE/256 exact (edgehead grid)
#define NBKT 196      // node-range buckets (256 nodes each)
#define NBLK 256      // edge chunks
#define EPB 3125      // NE/NBLK edges per chunk

typedef float v2f __attribute__((ext_vector_type(2)));
typedef float v4f __attribute__((ext_vector_type(4)));
typedef short bfrag __attribute__((ext_vector_type(8)));   // 8 bf16 = 4 VGPRs

__device__ __forceinline__ unsigned int packbf2(float a, float b) {
    __hip_bfloat162 h = __float22bfloat162_rn(make_float2(a, b));
    return *(unsigned int*)&h;
}
__device__ __forceinline__ v2f unpackbf2(unsigned int u) {
    v2f r;
    r.x = __uint_as_float(u << 16);
    r.y = __uint_as_float(u & 0xffff0000u);
    return r;
}
__device__ __forceinline__ bfrag cvt8(float4 a0, float4 a1) {
    union { uint4 u; bfrag f; } x;
    x.u.x = packbf2(a0.x, a0.y);
    x.u.y = packbf2(a0.z, a0.w);
    x.u.z = packbf2(a1.x, a1.y);
    x.u.w = packbf2(a1.z, a1.w);
    return x.f;
}
__device__ __forceinline__ bfrag cvt8v(v4f a0, v4f a1) {
    union { uint4 u; bfrag f; } x;
    x.u.x = packbf2(a0.x, a0.y);
    x.u.y = packbf2(a0.z, a0.w);
    x.u.z = packbf2(a1.x, a1.y);
    x.u.w = packbf2(a1.z, a1.w);
    return x.f;
}
#define COMP(u4, j) ((j) == 0 ? (u4).x : (j) == 1 ? (u4).y : (j) == 2 ? (u4).z : (u4).w)

// 16-lane add-reduce via DPP row_ror (VALU-only)
__device__ __forceinline__ float dpp_rowred16(float s) {
    s += __int_as_float(__builtin_amdgcn_update_dpp(0, __float_as_int(s), 0x121, 0xf, 0xf, false));
    s += __int_as_float(__builtin_amdgcn_update_dpp(0, __float_as_int(s), 0x122, 0xf, 0xf, false));
    s += __int_as_float(__builtin_amdgcn_update_dpp(0, __float_as_int(s), 0x124, 0xf, 0xf, false));
    s += __int_as_float(__builtin_amdgcn_update_dpp(0, __float_as_int(s), 0x128, 0xf, 0xf, false));
    return s;
}

// ---------------- Phase A: per-chunk LDS bucket histogram || weight preconvert ----
__global__ __launch_bounds__(256) void phaseA_k(const int* __restrict__ dst,
                                                int* __restrict__ bhist,
                                                const float* __restrict__ W1,
                                                const float* __restrict__ W2,
                                                const float* __restrict__ Ws,
                                                const float* __restrict__ Wd,
                                                const float* __restrict__ We,
                                                short* __restrict__ d1, short* __restrict__ d2,
                                                short* __restrict__ ds_, short* __restrict__ dd,
                                                unsigned int* __restrict__ WePk) {
    int b = blockIdx.x;
    if (b < NBLK) {
        __shared__ int lh[256];
        lh[threadIdx.x] = 0;
        __syncthreads();
        int base = b * EPB;
        for (int e = threadIdx.x; e < EPB; e += 256)
            atomicAdd(&lh[dst[base + e] >> 8], 1);
        __syncthreads();
        if (threadIdx.x < NBKT)
            bhist[threadIdx.x * NBLK + b] = lh[threadIdx.x];
        return;
    }
    b -= NBLK;
    if (b < 256) {
        int mat = b >> 6;
        const float* s = mat == 0 ? W1 : mat == 1 ? W2 : mat == 2 ? Ws : Wd;
        short* d = mat == 0 ? d1 : mat == 1 ? d2 : mat == 2 ? ds_ : dd;
        int idx = (b & 63) * 256 + threadIdx.x;   // 16384
        int n = idx & 127, k = idx >> 7;
        float v = s[k * 128 + n];
        d[n * 128 + k] = (short)(packbf2(v, v) & 0xffff);
    } else {
        int idx = (b - 256) * 256 + threadIdx.x;  // 0..2047
        int c = idx >> 8;
        int lane = (idx >> 2) & 63;
        int j2 = (idx & 3) * 2;
        int q = lane >> 4, i = lane & 15;
        int k0 = q * 8 + j2, k1 = k0 + 1;
        int feat = i * 8 + c;
        float v0 = (k0 < 16) ? We[k0 * 128 + feat] : 0.f;
        float v1 = (k1 < 16) ? We[k1 * 128 + feat] : 0.f;
        WePk[idx] = packbf2(v0, v1);
    }
}

// ---------------- Phase B: bucket scan + in-place rebase (1 block) ----------------
__global__ void phaseB_k(int* __restrict__ bhist, int* __restrict__ bucketBase,
                         int* __restrict__ bucketTot) {
    __shared__ int sh[256];
    int t = threadIdx.x;
    int tot = 0;
    if (t < NBKT)
        for (int blk = 0; blk < NBLK; blk++) tot += bhist[t * NBLK + blk];
    sh[t] = tot;
    __syncthreads();
    for (int off = 1; off < 256; off <<= 1) {
        int v = (t >= off) ? sh[t - off] : 0;
        __syncthreads();
        sh[t] += v;
        __syncthreads();
    }
    if (t < NBKT) {
        int base = sh[t] - tot;
        bucketBase[t] = base;
        bucketTot[t] = tot;
        int run = base;
        for (int blk = 0; blk < NBLK; blk++) {
            int h = bhist[t * NBLK + blk];
            bhist[t * NBLK + blk] = run;
            run += h;
        }
    }
}

// ---------------- Phase C: scatter edges into bucket-contiguous tmp (512 thr) ------
__global__ __launch_bounds__(512) void phaseC_k(const int* __restrict__ src,
                                                const int* __restrict__ dst,
                                                const int* __restrict__ bhist,
                                                unsigned int* __restrict__ tmp) {
    __shared__ int lcur[256];
    int b = blockIdx.x;
    if (threadIdx.x < NBKT)
        lcur[threadIdx.x] = bhist[threadIdx.x * NBLK + b];
    __syncthreads();
    int base = b * EPB;
    for (int e = threadIdx.x; e < EPB; e += 512) {
        int d = dst[base + e];
        int s = src[base + e];
        int pos = atomicAdd(&lcur[d >> 8], 1);
        tmp[pos] = (unsigned int)s | ((unsigned int)(d & 255) << 16);
    }
}

// ---------------- Phase D: per-bucket CSR finalize (512 thr) ----------------
__global__ __launch_bounds__(512) void fillb_k(const int* __restrict__ bucketBase,
                                               const int* __restrict__ bucketTot,
                                               const unsigned int* __restrict__ tmp,
                                               int* __restrict__ counts,
                                               int* __restrict__ offsets,
                                               float* __restrict__ dinv,
                                               int* __restrict__ srcs) {
    __shared__ int hist[256], off[256];
    int t = threadIdx.x;
    int b = blockIdx.x;
    if (t < 256) hist[t] = 0;
    __syncthreads();
    int base = bucketBase[b];
    int tot = bucketTot[b];
    const unsigned int* tp = tmp + base;
    for (int idx = t; idx < tot; idx += 512)
        atomicAdd(&hist[tp[idx] >> 16], 1);
    __syncthreads();
    int h = 0;
    if (t < 256) { h = hist[t]; off[t] = h; }
    __syncthreads();
    for (int o = 1; o < 256; o <<= 1) {
        int v = (t < 256 && t >= o) ? off[t - o] : 0;
        __syncthreads();
        if (t < 256) off[t] += v;
        __syncthreads();
    }
    if (t < 256) {
        int excl = off[t] - h;
        int node = b * 256 + t;
        if (node < NN) {
            counts[node] = h;
            offsets[node] = base + excl;
            dinv[node] = rsqrtf((float)h + 1.0f);
        }
        hist[t] = excl;    // reuse as per-node cursor
    }
    __syncthreads();
    for (int idx = t; idx < tot; idx += 512) {
        unsigned int u = tp[idx];
        int pos = atomicAdd(&hist[u >> 16], 1);
        srcs[base + pos] = (int)(u & 0xffffu);
    }
}

// ---------------- conv1 MFMA GEMM: hs1 = bf16((x @ W1) * dinv), row-major out ------
__global__ __launch_bounds__(256) void gemm1_k(const float* __restrict__ A,
                                               const short* __restrict__ Bt,
                                               unsigned int* __restrict__ Cb,
                                               const float* __restrict__ rowScale) {
    int lane = threadIdx.x & 63;
    int w = threadIdx.x >> 6;
    int i = lane & 15;
    int q = lane >> 4;
    int r0 = blockIdx.x * 64 + w * 16;
    int arow = min(r0 + i, NN - 1);
    const float* Arow = A + (size_t)arow * 128;

    v4f acc[8];
#pragma unroll
    for (int c = 0; c < 8; c++) acc[c] = (v4f)0.f;

#pragma unroll
    for (int kc = 0; kc < 128; kc += 32) {
        int kb = kc + q * 8;
        float4 a0 = *(const float4*)&Arow[kb];
        float4 a1 = *(const float4*)&Arow[kb + 4];
        bfrag af = cvt8(a0, a1);
#pragma unroll
        for (int c = 0; c < 8; c++) {
            bfrag bf = *(const bfrag*)&Bt[(size_t)(c * 16 + i) * 128 + kb];
            acc[c] = __builtin_amdgcn_mfma_f32_16x16x32_bf16(af, bf, acc[c], 0, 0, 0);
        }
    }

    int orow0 = r0 + q * 4;
    v4f ds = *(const v4f*)&rowScale[min(orow0, NN - 4)];
#pragma unroll
    for (int c = 0; c < 8; c++) {
        int col = c * 16 + i;
#pragma unroll
        for (int r = 0; r < 4; r++) {
            float v = acc[c][r] * ds[r];
            float vp = __shfl_xor(v, 1, 64);
            if (!(i & 1) && orow0 + r < NN)
                Cb[(size_t)(orow0 + r) * 64 + (col >> 1)] = packbf2(v, vp);
        }
    }
}

// ---------------- conv2 GEMM with BN-final fused in prologue, row-major out --------
__global__ __launch_bounds__(256) void gemm_bn_k(const unsigned int* __restrict__ Ab,
                                                 const short* __restrict__ Bt,
                                                 unsigned int* __restrict__ Cb,
                                                 const float* __restrict__ rowScale,
                                                 const float* __restrict__ sums,
                                                 const float* __restrict__ sumsq,
                                                 const float* __restrict__ gamma,
                                                 const float* __restrict__ beta) {
    __shared__ __align__(16) float tAs[128], tCs[128];
    if (threadIdx.x < 128) {
        int f = threadIdx.x;
        float mean = sums[f] * (1.0f / NN);
        float var = sumsq[f] * (1.0f / NN) - mean * mean;
        float a = gamma[f] * rsqrtf(var + BN_EPS);
        tAs[f] = a;
        tCs[f] = beta[f] - mean * a;
    }
    __syncthreads();

    int lane = threadIdx.x & 63;
    int w = threadIdx.x >> 6;
    int i = lane & 15;
    int q = lane >> 4;
    int r0 = blockIdx.x * 64 + w * 16;
    int arow = min(r0 + i, NN - 1);

    v4f acc[8];
#pragma unroll
    for (int c = 0; c < 8; c++) acc[c] = (v4f)0.f;

#pragma unroll
    for (int kc = 0; kc < 128; kc += 32) {
        int kb = kc + q * 8;
        uint4 u = *(const uint4*)&Ab[(size_t)arow * 64 + (kb >> 1)];
        v2f z0 = unpackbf2(u.x), z1 = unpackbf2(u.y);
        v2f z2 = unpackbf2(u.z), z3 = unpackbf2(u.w);
        v2f t0 = *(const v2f*)&tAs[kb],     c0 = *(const v2f*)&tCs[kb];
        v2f t1 = *(const v2f*)&tAs[kb + 2], c1 = *(const v2f*)&tCs[kb + 2];
        v2f t2 = *(const v2f*)&tAs[kb + 4], c2 = *(const v2f*)&tCs[kb + 4];
        v2f t3 = *(const v2f*)&tAs[kb + 6], c3 = *(const v2f*)&tCs[kb + 6];
        z0 = z0 * t0 + c0; z1 = z1 * t1 + c1;
        z2 = z2 * t2 + c2; z3 = z3 * t3 + c3;
        union { uint4 u; bfrag f; } x;
        x.u.x = packbf2(fmaxf(z0.x, 0.f), fmaxf(z0.y, 0.f));
        x.u.y = packbf2(fmaxf(z1.x, 0.f), fmaxf(z1.y, 0.f));
        x.u.z = packbf2(fmaxf(z2.x, 0.f), fmaxf(z2.y, 0.f));
        x.u.w = packbf2(fmaxf(z3.x, 0.f), fmaxf(z3.y, 0.f));
        bfrag af = x.f;
#pragma unroll
        for (int c = 0; c < 8; c++) {
            bfrag bf = *(const bfrag*)&Bt[(size_t)(c * 16 + i) * 128 + kb];
            acc[c] = __builtin_amdgcn_mfma_f32_16x16x32_bf16(af, bf, acc[c], 0, 0, 0);
        }
    }

    int orow0 = r0 + q * 4;
    v4f ds = *(const v4f*)&rowScale[min(orow0, NN - 4)];
#pragma unroll
    for (int c = 0; c < 8; c++) {
        int col = c * 16 + i;
#pragma unroll
        for (int r = 0; r < 4; r++) {
            float v = acc[c][r] * ds[r];
            float vp = __shfl_xor(v, 1, 64);
            if (!(i & 1) && orow0 + r < NN)
                Cb[(size_t)(orow0 + r) * 64 + (col >> 1)] = packbf2(v, vp);
        }
    }
}

// ---------------- merged P/Q MFMA GEMM (A bf16-packed): P=A@Bs (bf16), Q=A@Bd+bm1 (bf16) ----
__global__ __launch_bounds__(256) void gemm_pq(const unsigned int* __restrict__ zbA,
                                               const short* __restrict__ Bs_,
                                               const short* __restrict__ Bd_,
                                               const float* __restrict__ bm1,
                                               unsigned int* __restrict__ Pb,
                                               unsigned int* __restrict__ Qb,
                                               int M) {
    int lane = threadIdx.x & 63;
    int w = threadIdx.x >> 6;
    int i = lane & 15;
    int q = lane >> 4;
    int r0 = blockIdx.x * 64 + w * 16;
    int arow = min(r0 + i, M - 1);

    v4f accP[8], accQ[8];
#pragma unroll
    for (int c = 0; c < 8; c++) { accP[c] = (v4f)0.f; accQ[c] = (v4f)0.f; }

#pragma unroll
    for (int kc = 0; kc < 128; kc += 32) {
        int kb = kc + q * 8;
        bfrag af = *(const bfrag*)&zbA[(size_t)arow * 64 + (kb >> 1)];
#pragma unroll
        for (int c = 0; c < 8; c++) {
            bfrag bs = *(const bfrag*)&Bs_[(size_t)(c * 16 + i) * 128 + kb];
            bfrag bd = *(const bfrag*)&Bd_[(size_t)(c * 16 + i) * 128 + kb];
            accP[c] = __builtin_amdgcn_mfma_f32_16x16x32_bf16(af, bs, accP[c], 0, 0, 0);
            accQ[c] = __builtin_amdgcn_mfma_f32_16x16x32_bf16(af, bd, accQ[c], 0, 0, 0);
        }
    }

    int orow0 = r0 + q * 4;
    float bm1c[8];
#pragma unroll
    for (int c = 0; c < 8; c++) bm1c[c] = bm1[c * 16 + i];
#pragma unroll
    for (int c = 0; c < 8; c++) {
        int col = c * 16 + i;
#pragma unroll
        for (int r = 0; r < 4; r++) {
            float vP = accP[c][r];
            float vPp = __shfl_xor(vP, 1, 64);
            float vQ = accQ[c][r] + bm1c[c];
            float vQp = __shfl_xor(vQ, 1, 64);
            if (!(i & 1) && orow0 + r < M) {
                Pb[(size_t)(orow0 + r) * 64 + (col >> 1)] = packbf2(vP, vPp);
                Qb[(size_t)(orow0 + r) * 64 + (col >> 1)] = packbf2(vQ, vQp);
            }
        }
    }
}

// ---------------- aggregation (r8-verbatim): z[n] = dinv*(sum hs[src] + hs[n]) + b ----
// Quadrant-gather, single pass over full 256B rows, 4 independent 4-row gathers in
// flight per iteration (r10/r11 lesson: multi-pass slicing is 2x slower regardless
// of layout — serialized single-gather inner loop + per-pass overhead dominate).
// All __shfl under FULL exec (round-4 lesson).
__global__ __launch_bounds__(256) void aggregate_k(const unsigned int* __restrict__ hsb,
                                                   const int* __restrict__ offsets,
                                                   const int* __restrict__ counts,
                                                   const int* __restrict__ srcs,
                                                   const float* __restrict__ dinv,
                                                   const float* __restrict__ bias,
                                                   unsigned int* __restrict__ zbout) {
    int lane = threadIdx.x & 63;
    int i = lane & 15;
    int q = lane >> 4;
    int n = __builtin_amdgcn_readfirstlane(blockIdx.x * 4 + (threadIdx.x >> 6));
    if (n >= NN) return;
    int beg = offsets[n];
    int cnt = counts[n];
    v2f A0 = {0.f, 0.f}, A1 = {0.f, 0.f}, A2 = {0.f, 0.f}, A3 = {0.f, 0.f};
    v2f B0 = {0.f, 0.f}, B1 = {0.f, 0.f}, B2 = {0.f, 0.f}, B3 = {0.f, 0.f};
    for (int c = 0; c < cnt; c += 64) {
        int vsrc = srcs[beg + c + lane];
        int m = min(64, cnt - c);
        int ngrp = m >> 2;
        int g = 0;
        for (; g + 4 <= ngrp; g += 4) {
            int s0 = __shfl(vsrc, g * 4 + q, 64);
            int s1 = __shfl(vsrc, g * 4 + 4 + q, 64);
            int s2 = __shfl(vsrc, g * 4 + 8 + q, 64);
            int s3 = __shfl(vsrc, g * 4 + 12 + q, 64);
            uint4 u0 = *(const uint4*)&hsb[(size_t)s0 * 64 + i * 4];
            uint4 u1 = *(const uint4*)&hsb[(size_t)s1 * 64 + i * 4];
            uint4 u2 = *(const uint4*)&hsb[(size_t)s2 * 64 + i * 4];
            uint4 u3 = *(const uint4*)&hsb[(size_t)s3 * 64 + i * 4];
            A0 += unpackbf2(u0.x); A1 += unpackbf2(u0.y); A2 += unpackbf2(u0.z); A3 += unpackbf2(u0.w);
            B0 += unpackbf2(u1.x); B1 += unpackbf2(u1.y); B2 += unpackbf2(u1.z); B3 += unpackbf2(u1.w);
            A0 += unpackbf2(u2.x); A1 += unpackbf2(u2.y); A2 += unpackbf2(u2.z); A3 += unpackbf2(u2.w);
            B0 += unpackbf2(u3.x); B1 += unpackbf2(u3.y); B2 += unpackbf2(u3.z); B3 += unpackbf2(u3.w);
        }
        for (; g < ngrp; g++) {
            int s0 = __shfl(vsrc, g * 4 + q, 64);
            uint4 u0 = *(const uint4*)&hsb[(size_t)s0 * 64 + i * 4];
            A0 += unpackbf2(u0.x); A1 += unpackbf2(u0.y); A2 += unpackbf2(u0.z); A3 += unpackbf2(u0.w);
        }
        int rem = m & 3;
        if (rem) {
            int s0 = __shfl(vsrc, (m & ~3) + q, 64);   // FULL-exec shfl (uniform branch)
            if (q < rem) {
                uint4 u0 = *(const uint4*)&hsb[(size_t)s0 * 64 + i * 4];
                B0 += unpackbf2(u0.x); B1 += unpackbf2(u0.y); B2 += unpackbf2(u0.z); B3 += unpackbf2(u0.w);
            }
        }
    }
    A0 += B0; A1 += B1; A2 += B2; A3 += B3;
    A0.x += __shfl_xor(A0.x, 32, 64); A0.y += __shfl_xor(A0.y, 32, 64);
    A1.x += __shfl_xor(A1.x, 32, 64); A1.y += __shfl_xor(A1.y, 32, 64);
    A2.x += __shfl_xor(A2.x, 32, 64); A2.y += __shfl_xor(A2.y, 32, 64);
    A3.x += __shfl_xor(A3.x, 32, 64); A3.y += __shfl_xor(A3.y, 32, 64);
    bool hi = (lane & 32) != 0;
    v2f U0, U1;
    U0.x = hi ? A2.x : A0.x; U0.y = hi ? A2.y : A0.y;
    U1.x = hi ? A3.x : A1.x; U1.y = hi ? A3.y : A1.y;
    U0.x += __shfl_xor(U0.x, 16, 64); U0.y += __shfl_xor(U0.y, 16, 64);
    U1.x += __shfl_xor(U1.x, 16, 64); U1.y += __shfl_xor(U1.y, 16, 64);
    bool lo = (lane & 16) != 0;
    v2f res;
    res.x = lo ? U1.x : U0.x;
    res.y = lo ? U1.y : U0.y;
    int ui = i * 4 + q;
    v2f self = unpackbf2(hsb[(size_t)n * 64 + ui]);
    float di = dinv[n];
    float2 b = *(const float2*)&bias[ui * 2];
    float rx = (res.x + self.x) * di + b.x;
    float ry = (res.y + self.y) * di + b.y;
    zbout[(size_t)n * 64 + ui] = packbf2(rx, ry);
}

// ---------------- BatchNorm stats (bf16-packed row-major input) ----------------
__global__ __launch_bounds__(256) void bnstats_b_k(const unsigned int* __restrict__ zb,
                                                   float* __restrict__ sums,
                                                   float* __restrict__ sumsq) {
    __shared__ v2f ls[4][64], lq[4][64];
    int lane = threadIdx.x & 63;   // feature pair
    int sub = threadIdx.x >> 6;    // 4 rows in parallel
    v2f s = {0.f, 0.f}, q = {0.f, 0.f};
    for (int r = blockIdx.x * 4 + sub; r < NN; r += gridDim.x * 4) {
        v2f v = unpackbf2(zb[(size_t)r * 64 + lane]);
        s += v;
        q += v * v;
    }
    if (sub) { ls[sub][lane] = s; lq[sub][lane] = q; }
    __syncthreads();
    if (!sub) {
        s += ls[1][lane] + ls[2][lane] + ls[3][lane];
        q += lq[1][lane] + lq[2][lane] + lq[3][lane];
        atomicAdd(&sums[lane * 2], s.x);
        atomicAdd(&sums[lane * 2 + 1], s.y);
        atomicAdd(&sumsq[lane * 2], q.x);
        atomicAdd(&sumsq[lane * 2 + 1], q.y);
    }
}

// ---------------- edge head: MFMA in ORIGINAL edge order (round-8 verbatim) --------
__global__ __launch_bounds__(256) void edgehead_k(const unsigned int* __restrict__ Pb,
                                                  const unsigned int* __restrict__ Qb,
                                                  const float* __restrict__ ea,
                                                  const int* __restrict__ srcI,
                                                  const int* __restrict__ dstI,
                                                  const unsigned int* __restrict__ WePk,
                                                  const float* __restrict__ Wm2,
                                                  const float* __restrict__ bm2,
                                                  float* __restrict__ out) {
    int lane = threadIdx.x & 63;
    int wid = threadIdx.x >> 6;
    int base = (blockIdx.x * 4 + wid) * 64;
    int i = lane & 15;
    int q = lane >> 4;

    bfrag wef[8];
#pragma unroll
    for (int c = 0; c < 8; c++)
        wef[c] = *(const bfrag*)&WePk[(c * 64 + lane) * 4];
    float4 wv0 = *(const float4*)&Wm2[i * 8];
    float4 wv1 = *(const float4*)&Wm2[i * 8 + 4];
    v2f wv2[4];
    wv2[0].x = wv0.x; wv2[0].y = wv0.y;
    wv2[1].x = wv0.z; wv2[1].y = wv0.w;
    wv2[2].x = wv1.x; wv2[2].y = wv1.y;
    wv2[3].x = wv1.z; wv2[3].y = wv1.w;
    float bm2v = bm2[0];

    int sv = srcI[base + lane];
    int dv = dstI[base + lane];

#pragma unroll
    for (int t = 0; t < 4; t++) {
        int tb = t * 16;
        bfrag af;
#pragma unroll
        for (int z = 0; z < 8; z++) af[z] = 0;
        if (q < 2) {
            const float* erow = &ea[(size_t)(base + tb + i) * 16 + q * 8];
            v4f e0 = __builtin_nontemporal_load((const v4f*)erow);
            v4f e1 = __builtin_nontemporal_load((const v4f*)(erow + 4));
            af = cvt8v(e0, e1);
        }
        uint4 Pu[4], Qu[4];
#pragma unroll
        for (int r = 0; r < 4; r++) {
            int sr = __shfl(sv, tb + q * 4 + r, 64);
            int dr = __shfl(dv, tb + q * 4 + r, 64);
            Pu[r] = *(const uint4*)&Pb[(size_t)sr * 64 + i * 4];
            Qu[r] = *(const uint4*)&Qb[(size_t)dr * 64 + i * 4];
        }
        v4f acc[8];
#pragma unroll
        for (int c = 0; c < 8; c++) acc[c] = (v4f)0.f;
#pragma unroll
        for (int c = 0; c < 8; c++)
            acc[c] = __builtin_amdgcn_mfma_f32_16x16x32_bf16(af, wef[c], acc[c], 0, 0, 0);
#pragma unroll
        for (int r = 0; r < 4; r++) {
            v2f sa = {0.f, 0.f};
#pragma unroll
            for (int j = 0; j < 4; j++) {
                v2f pq = unpackbf2(COMP(Pu[r], j)) + unpackbf2(COMP(Qu[r], j));
                v2f tt;
                tt.x = acc[2 * j][r] + pq.x;
                tt.y = acc[2 * j + 1][r] + pq.y;
                tt.x = fmaxf(tt.x, 0.f);
                tt.y = fmaxf(tt.y, 0.f);
                sa += tt * wv2[j];
            }
            float s = dpp_rowred16(sa.x + sa.y);
            if (i == 0) __builtin_nontemporal_store(s + bm2v, &out[base + tb + q * 4 + r]);
        }
    }
}

// ---------------- launcher ----------------
extern "C" void kernel_launch(void* const* d_in, const int* in_sizes, int n_in,
                              void* d_out, int out_size, void* d_ws, size_t ws_size,
                              hipStream_t stream) {
    const float* x     = (const float*)d_in[0];
    const int*   ei    = (const int*)d_in[1];
    const float* ea    = (const float*)d_in[2];
    const float* W1    = (const float*)d_in[3];
    const float* b1    = (const float*)d_in[4];
    const float* gamma = (const float*)d_in[5];
    const float* beta  = (const float*)d_in[6];
    const float* W2    = (const float*)d_in[7];
    const float* b2    = (const float*)d_in[8];
    const float* Wm1   = (const float*)d_in[9];
    const float* bm1   = (const float*)d_in[10];
    const float* Wm2   = (const float*)d_in[11];
    const float* bm2   = (const float*)d_in[12];
    float* out = (float*)d_out;

    const int* srcI = ei;
    const int* dstI = ei + NE;

    char* w = (char*)d_ws;
    auto alloc = [&](size_t bytes) {
        char* p = w;
        w += (bytes + 255) & ~(size_t)255;
        return p;
    };
    // zero region: sums | sumsq — one small memset
    float* sums    = (float*)alloc(256 * 4);
    float* sumsq   = sums + 128;
    int*   bhist   = (int*)alloc(NBKT * NBLK * 4);     // 200 KB
    int*   bucketBase = (int*)alloc(NBKT * 4);
    int*   bucketTot  = (int*)alloc(NBKT * 4);
    unsigned int* tmp = (unsigned int*)alloc((size_t)NE * 4);   // 3.2 MB
    int*   counts  = (int*)alloc(NN * 4);
    int*   offsets = (int*)alloc(NN * 4);
    float* dinv    = (float*)alloc(NN * 4);
    int*   srcs    = (int*)alloc((size_t)(NE + 64) * 4);
    short* bt1     = (short*)alloc(128 * 128 * 2);
    short* bt2     = (short*)alloc(128 * 128 * 2);
    short* bts     = (short*)alloc(128 * 128 * 2);
    short* btd     = (short*)alloc(128 * 128 * 2);
    unsigned int* WePk = (unsigned int*)alloc(2048 * 4);
    unsigned int* hsb  = (unsigned int*)alloc((size_t)NN * 64 * 4);   // hs / P table
    unsigned int* zb1  = (unsigned int*)alloc((size_t)NN * 64 * 4);   // z1 bf16; later z2 (aliased)
    unsigned int* Qb   = (unsigned int*)alloc((size_t)NN * 64 * 4);   // Q table
    unsigned int* zb2  = zb1;   // alias: z1 dead after conv2 GEMM reads it

    hipMemsetAsync(sums, 0, 256 * 4, stream);

    // K1: per-chunk bucket histograms || weight preconvert
    phaseA_k<<<NBLK + 264, 256, 0, stream>>>(dstI, bhist, W1, W2, Wm1,
                                             Wm1 + 128 * 128, Wm1 + 256 * 128,
                                             bt1, bt2, bts, btd, WePk);
    // K2: bucket scan + rebase
    phaseB_k<<<1, 256, 0, stream>>>(bhist, bucketBase, bucketTot);
    // K3: scatter to bucket-contiguous tmp (no global atomics)
    phaseC_k<<<NBLK, 512, 0, stream>>>(srcI, dstI, bhist, tmp);
    // K4: per-bucket CSR finalize (counts/offsets/dinv/srcs)
    fillb_k<<<NBKT, 512, 0, stream>>>(bucketBase, bucketTot, tmp,
                                      counts, offsets, dinv, srcs);

    const int GB = (NN + 63) / 64;   // 782
    const int AGG = (NN + 3) / 4;    // 12500

    // K5: conv1 GEMM (hs1 = (x@W1)*dinv -> bf16 row-major)
    gemm1_k<<<GB, 256, 0, stream>>>(x, bt1, hsb, dinv);
    // K6: agg1 -> z1 (bf16), single pass
    aggregate_k<<<AGG, 256, 0, stream>>>(hsb, offsets, counts, srcs, dinv, b1, zb1);
    // K7: BN stats
    bnstats_b_k<<<256, 256, 0, stream>>>(zb1, sums, sumsq);
    // K8: conv2 GEMM, BN-final fused in prologue
    gemm_bn_k<<<GB, 256, 0, stream>>>(zb1, bt2, hsb, dinv, sums, sumsq, gamma, beta);
    // K9: agg2 -> z2 (aliases zb1), single pass
    aggregate_k<<<AGG, 256, 0, stream>>>(hsb, offsets, counts, srcs, dinv, b2, zb2);
    // K10: edge head precompute P/Q
    gemm_pq<<<GB, 256, 0, stream>>>(zb2, bts, btd, bm1, hsb, Qb, NN);
    // K11: edge head (r8 structure: 256 edges/block)
    edgehead_k<<<NB_E, 256, 0, stream>>>(hsb, Qb, ea, srcI, dstI, WePk,
                                         Wm2, bm2, out);
}